// Round 3
// baseline (784.285 us; speedup 1.0000x reference)
//
#include <hip/hip_runtime.h>

#define BATCH 16384
#define KDIM  8192
#define ODIM  32
#define SK    4                   // split-K across blocks
#define KSLICE (KDIM / SK)        // 2048 k per block
#define NWAVE 4
#define THREADS (NWAVE * 64)
#define KW    (KSLICE / NWAVE)    // 512 k per wave
#define KT    16                  // k per tile
#define NT    (KW / KT)           // 32 tiles per wave

// ---------------------------------------------------------------------------
// Prep 1: bwT[k][o] = sign(w[o][k]) as +-1.0f/0, + per-block partial sum |w|
// ---------------------------------------------------------------------------
__global__ void prep_kernel(const float* __restrict__ w,
                            float* __restrict__ bwT,
                            float* __restrict__ partial) {
    int idx = blockIdx.x * 256 + threadIdx.x;   // coalesced over 32*8192
    int o = idx >> 13;
    int k = idx & (KDIM - 1);
    float v = w[idx];
    float s = (v > 0.f) ? 1.f : ((v < 0.f) ? -1.f : 0.f);
    bwT[(size_t)k * ODIM + o] = s;

    float a = fabsf(v);
    #pragma unroll
    for (int off = 32; off; off >>= 1) a += __shfl_down(a, off, 64);
    __shared__ float red[4];
    int lane = threadIdx.x & 63, wv = threadIdx.x >> 6;
    if (lane == 0) red[wv] = a;
    __syncthreads();
    if (threadIdx.x == 0)
        partial[blockIdx.x] = (red[0] + red[1]) + (red[2] + red[3]);
}

// ---------------------------------------------------------------------------
// Prep 2: deterministic reduce of 1024 partials -> scale = mean(|w|)
// ---------------------------------------------------------------------------
__global__ void scale_kernel(const float* __restrict__ partial,
                             float* __restrict__ scale) {
    int t = threadIdx.x;  // 256 threads
    float a = (partial[t] + partial[t + 256]) + (partial[t + 512] + partial[t + 768]);
    #pragma unroll
    for (int off = 32; off; off >>= 1) a += __shfl_down(a, off, 64);
    __shared__ float red[4];
    if ((t & 63) == 0) red[t >> 6] = a;
    __syncthreads();
    if (t == 0)
        scale[0] = ((red[0] + red[1]) + (red[2] + red[3])) / (float)(ODIM * KDIM);
}

// ---------------------------------------------------------------------------
// Main: wave-private double-buffered LDS staging (NO block barriers in the
// K-loop; all waits are wave-local s_waitcnt). lane = row -> weights are
// wave-uniform scalar loads. Split-K partials, no atomics.
// grid = 256 row-groups x SK = 1024 blocks x 256 threads.
// ---------------------------------------------------------------------------
__global__ __launch_bounds__(THREADS, 4)
void main_kernel(const float* __restrict__ x,
                 const float* __restrict__ bwT,
                 float* __restrict__ pout) {
    __shared__ union {
        float4 buf[NWAVE * 2 * 64 * 4];   // per wave: 2 bufs x 64 rows x 4 f4 slots = 32 KB total
        float  part[NWAVE][ODIM][65];     // 33280 B cross-wave reduce staging
    } sm;

    const int tid  = threadIdx.x;
    const int wv   = tid >> 6;
    const int lane = tid & 63;
    const int rb   = blockIdx.x >> 2;
    const int kb   = blockIdx.x & (SK - 1);
    const size_t rowbase = (size_t)rb * 64;
    const int kbase = kb * KSLICE + wv * KW;

    const int r0 = lane >> 2;   // 0..15  (row within 16-row group)
    const int k4 = lane & 3;    // 0..3   (float4 column within tile)

    // 4 global base pointers; per unrolled-2 iter they advance 32 floats,
    // within an iter tiles are reached via immediate offsets.
    const float* xp0 = x + (rowbase + r0 +  0) * (size_t)KDIM + kbase + k4 * 4;
    const float* xp1 = x + (rowbase + r0 + 16) * (size_t)KDIM + kbase + k4 * 4;
    const float* xp2 = x + (rowbase + r0 + 32) * (size_t)KDIM + kbase + k4 * 4;
    const float* xp3 = x + (rowbase + r0 + 48) * (size_t)KDIM + kbase + k4 * 4;

    // LDS addressing (float4 units). XOR slot swizzle: store (r,k4) at slot
    // k4^(r&3); read logical q at slot q^(lane&3) -> retrieves k4=q.
    float4* wbase = &sm.buf[wv * 512];
    float4* wr = wbase + r0 * 4 + (k4 ^ (r0 & 3));          // rows r0+16i at +64*i
    const float4* rd0 = wbase + lane * 4 + (0 ^ (lane & 3));
    const float4* rd1 = wbase + lane * 4 + (1 ^ (lane & 3));
    const float4* rd2 = wbase + lane * 4 + (2 ^ (lane & 3));
    const float4* rd3 = wbase + lane * 4 + (3 ^ (lane & 3));

    float acc[ODIM];
    #pragma unroll
    for (int o = 0; o < ODIM; ++o) acc[o] = 0.f;

    float4 A0, A1, A2, A3, B0, B1, B2, B3;

#define LOADT(d0, d1, d2, d3, toff) do {                    \
        d0 = *(const float4*)(xp0 + (toff) * KT);           \
        d1 = *(const float4*)(xp1 + (toff) * KT);           \
        d2 = *(const float4*)(xp2 + (toff) * KT);           \
        d3 = *(const float4*)(xp3 + (toff) * KT); } while (0)

#define STORET(s0, s1, s2, s3, cur) do {                    \
        wr[(cur) * 256 +   0] = s0;                         \
        wr[(cur) * 256 +  64] = s1;                         \
        wr[(cur) * 256 + 128] = s2;                         \
        wr[(cur) * 256 + 192] = s3; } while (0)

#define COMPUTET(cur, wt) do {                                              \
        float4 xa = rd0[(cur) * 256], xb = rd1[(cur) * 256];                \
        float4 xc = rd2[(cur) * 256], xd = rd3[(cur) * 256];                \
        const float xs[16] = {xa.x, xa.y, xa.z, xa.w, xb.x, xb.y, xb.z, xb.w, \
                              xc.x, xc.y, xc.z, xc.w, xd.x, xd.y, xd.z, xd.w}; \
        _Pragma("unroll")                                                   \
        for (int kk = 0; kk < 16; ++kk) {                                   \
            const float* __restrict__ wo = (wt) + kk * ODIM;                \
            _Pragma("unroll")                                               \
            for (int o = 0; o < ODIM; ++o)                                  \
                acc[o] = fmaf(xs[kk], wo[o], acc[o]);                       \
        } } while (0)

    // prologue: tile0 -> buf0 (one vmcnt(0) stall), tile1 in flight in A
    LOADT(A0, A1, A2, A3, 0);
    STORET(A0, A1, A2, A3, 0);
    LOADT(A0, A1, A2, A3, 1);

    const float* wt = bwT + (size_t)kbase * ODIM;

    for (int t2 = 0; t2 < NT; t2 += 2) {
        // even tile t2 (buf0)
        if (t2 + 2 < NT) LOADT(B0, B1, B2, B3, 2);
        if (t2 + 1 < NT) STORET(A0, A1, A2, A3, 1);   // tile t2+1 -> buf1
        COMPUTET(0, wt);
        // odd tile t2+1 (buf1)
        if (t2 + 3 < NT) LOADT(A0, A1, A2, A3, 3);
        if (t2 + 2 < NT) STORET(B0, B1, B2, B3, 0);   // tile t2+2 -> buf0
        COMPUTET(1, wt + 16 * ODIM);

        xp0 += 32; xp1 += 32; xp2 += 32; xp3 += 32;
        wt += 32 * ODIM;
    }

#undef LOADT
#undef STORET
#undef COMPUTET

    // cross-wave reduce: barrier before overwriting other waves' x-buffers
    __syncthreads();
    #pragma unroll
    for (int o = 0; o < ODIM; ++o) sm.part[wv][o][lane] = acc[o];
    __syncthreads();

    float* __restrict__ pb = pout + ((size_t)kb * BATCH + rowbase) * ODIM;
    #pragma unroll
    for (int i = 0; i < 8; ++i) {
        int j = tid + THREADS * i;        // j = r*32 + o, fully coalesced
        int r = j >> 5, o = j & 31;
        float s = (sm.part[0][o][r] + sm.part[1][o][r]) +
                  (sm.part[2][o][r] + sm.part[3][o][r]);
        pb[j] = s;
    }
}

// ---------------------------------------------------------------------------
// Final: out = (p0+p1+p2+p3) * scale, float4-vectorized, deterministic
// ---------------------------------------------------------------------------
__global__ void reduce_kernel(const float* __restrict__ pout,
                              const float* __restrict__ scale_p,
                              float* __restrict__ out) {
    const int STRIDE = BATCH * ODIM / 4;          // float4 per split slice
    int i = blockIdx.x * 256 + threadIdx.x;       // grid 512 x 256
    const float s = scale_p[0];
    const float4* p = (const float4*)pout;
    float4 a = p[i], b = p[i + STRIDE], c = p[i + 2 * STRIDE], d = p[i + 3 * STRIDE];
    float4 r;
    r.x = ((a.x + b.x) + (c.x + d.x)) * s;
    r.y = ((a.y + b.y) + (c.y + d.y)) * s;
    r.z = ((a.z + b.z) + (c.z + d.z)) * s;
    r.w = ((a.w + b.w) + (c.w + d.w)) * s;
    ((float4*)out)[i] = r;
}

// ---------------------------------------------------------------------------
extern "C" void kernel_launch(void* const* d_in, const int* in_sizes, int n_in,
                              void* d_out, int out_size, void* d_ws, size_t ws_size,
                              hipStream_t stream) {
    const float* x = (const float*)d_in[0];
    const float* w = (const float*)d_in[1];
    float* out = (float*)d_out;

    float* wsf     = (float*)d_ws;
    float* partial = wsf;                       // 1024 floats
    float* scale   = wsf + 1024;                // 1 float
    float* bwT     = wsf + 2048;                // 262144 floats (1 MiB)
    float* pout    = wsf + 2048 + ODIM * KDIM;  // SK * 524288 floats (8 MiB)

    prep_kernel<<<1024, 256, 0, stream>>>(w, bwT, partial);
    scale_kernel<<<1, 256, 0, stream>>>(partial, scale);
    main_kernel<<<(BATCH / 64) * SK, THREADS, 0, stream>>>(x, bwT, pout);
    reduce_kernel<<<BATCH * ODIM / 4 / 256, 256, 0, stream>>>(pout, scale, out);
}

// Round 4
// 218.273 us; speedup vs baseline: 3.5931x; 3.5931x over previous
//
#include <hip/hip_runtime.h>

#define BATCH 16384
#define KDIM  8192
#define ODIM  32
#define SK    4                   // split-K across blocks
#define KSLICE (KDIM / SK)        // 2048 k per block
#define NWAVE 4
#define THREADS (NWAVE * 64)
#define KW    (KSLICE / NWAVE)    // 512 k per wave
#define KT    16                  // k per wave-tile
#define NT    (KW / KT)           // 32 tiles per wave

// direct global->LDS, 16B per lane; dest = wave-uniform base + lane*16
__device__ __forceinline__ void gload16(const float* g, float4* l) {
    __builtin_amdgcn_global_load_lds(
        (const __attribute__((address_space(1))) void*)g,
        (__attribute__((address_space(3))) void*)l, 16, 0, 0);
}

// ---------------------------------------------------------------------------
// Prep 1: bwT[k][o] = sign(w[o][k]) as +-1.0f/0, + per-block partial sum |w|
// ---------------------------------------------------------------------------
__global__ void prep_kernel(const float* __restrict__ w,
                            float* __restrict__ bwT,
                            float* __restrict__ partial) {
    int idx = blockIdx.x * 256 + threadIdx.x;
    int o = idx >> 13;
    int k = idx & (KDIM - 1);
    float v = w[idx];
    float s = (v > 0.f) ? 1.f : ((v < 0.f) ? -1.f : 0.f);
    bwT[(size_t)k * ODIM + o] = s;

    float a = fabsf(v);
    #pragma unroll
    for (int off = 32; off; off >>= 1) a += __shfl_down(a, off, 64);
    __shared__ float red[4];
    int lane = threadIdx.x & 63, wv = threadIdx.x >> 6;
    if (lane == 0) red[wv] = a;
    __syncthreads();
    if (threadIdx.x == 0)
        partial[blockIdx.x] = (red[0] + red[1]) + (red[2] + red[3]);
}

__global__ void scale_kernel(const float* __restrict__ partial,
                             float* __restrict__ scale) {
    int t = threadIdx.x;
    float a = (partial[t] + partial[t + 256]) + (partial[t + 512] + partial[t + 768]);
    #pragma unroll
    for (int off = 32; off; off >>= 1) a += __shfl_down(a, off, 64);
    __shared__ float red[4];
    if ((t & 63) == 0) red[t >> 6] = a;
    __syncthreads();
    if (t == 0)
        scale[0] = ((red[0] + red[1]) + (red[2] + red[3])) / (float)(ODIM * KDIM);
}

// ---------------------------------------------------------------------------
// Main: global_load_lds direct staging into wave-private double buffers.
// No block barriers in K-loop; counted vmcnt(4) keeps 1 tile in flight.
// lane = row -> weights wave-uniform (readfirstlane-forced) -> s_load.
// ---------------------------------------------------------------------------
__global__ __launch_bounds__(THREADS, 4)
void main_kernel(const float* __restrict__ x,
                 const float* __restrict__ bwT,
                 float* __restrict__ pout) {
    __shared__ union {
        float4 buf[2048];               // 4 waves x 2 bufs x 256 float4 = 32 KB
        float  part[NWAVE][ODIM][65];   // cross-wave reduce staging
    } sm;

    const int tid  = threadIdx.x;
    const int wv   = __builtin_amdgcn_readfirstlane(tid >> 6);  // MUST be SGPR
    const int lane = tid & 63;
    const int rb   = blockIdx.x >> 2;
    const int kb   = blockIdx.x & (SK - 1);
    const size_t rowbase = (size_t)rb * 64;
    const int kbase = kb * KSLICE + wv * KW;

    // source swizzle: lane loads (row = i*16 + lane/4, chunk q) so that the
    // LINEAR lds dest (slot = i*64+lane) equals slot(r,q) = 4r + (q^((r>>2)&3))
    const int q  = (lane & 3) ^ ((lane >> 4) & 3);
    const int sw = (lane >> 2) & 3;

    const float* gp0 = x + (rowbase + (lane >> 2)) * (size_t)KDIM + kbase + 4 * q;
    const float* gp1 = gp0 + (size_t)16 * KDIM;
    const float* gp2 = gp0 + (size_t)32 * KDIM;
    const float* gp3 = gp0 + (size_t)48 * KDIM;

    float4* const wbuf = &sm.buf[wv * 512];   // this wave's 2 x 256 float4

    float acc[ODIM];
    #pragma unroll
    for (int o = 0; o < ODIM; ++o) acc[o] = 0.f;

#define ISSUE(db, toff) do {                         \
        float4* lb = wbuf + (db) * 256;              \
        gload16(gp0 + (toff) * KT, lb);              \
        gload16(gp1 + (toff) * KT, lb + 64);         \
        gload16(gp2 + (toff) * KT, lb + 128);        \
        gload16(gp3 + (toff) * KT, lb + 192);        \
    } while (0)

#define FMA16(wtp) do {                                              \
        const float xs[16] = {x0.x, x0.y, x0.z, x0.w,                \
                              x1.x, x1.y, x1.z, x1.w,                \
                              x2.x, x2.y, x2.z, x2.w,                \
                              x3.x, x3.y, x3.z, x3.w};               \
        _Pragma("unroll")                                            \
        for (int kk = 0; kk < 16; ++kk) {                            \
            const float* __restrict__ wo = (wtp) + kk * ODIM;        \
            _Pragma("unroll")                                        \
            for (int o = 0; o < ODIM; ++o)                           \
                acc[o] = fmaf(xs[kk], wo[o], acc[o]);                \
        }                                                            \
    } while (0)

    ISSUE(0, 0);      // tile 0 -> buf0
    ISSUE(1, 1);      // tile 1 -> buf1

    const float* wt = bwT + (size_t)kbase * ODIM;
    const float4* const rd0 = wbuf + 4 * lane;         // buf0 read base
    const float4* const rd1 = wbuf + 256 + 4 * lane;   // buf1 read base

    for (int t2 = 0; t2 < NT - 2; t2 += 2) {
        {   // tile t2 (buf0); outstanding {t2,t2+1}=8 -> retire t2's 4
            asm volatile("s_waitcnt vmcnt(4)" ::: "memory");
            float4 x0 = rd0[0 ^ sw], x1 = rd0[1 ^ sw];
            float4 x2 = rd0[2 ^ sw], x3 = rd0[3 ^ sw];
            ISSUE(0, 2);                       // tile t2+2 -> buf0
            FMA16(wt);
        }
        {   // tile t2+1 (buf1)
            asm volatile("s_waitcnt vmcnt(4)" ::: "memory");
            float4 x0 = rd1[0 ^ sw], x1 = rd1[1 ^ sw];
            float4 x2 = rd1[2 ^ sw], x3 = rd1[3 ^ sw];
            ISSUE(1, 3);                       // tile t2+3 -> buf1
            FMA16(wt + KT * ODIM);
        }
        gp0 += 2 * KT; gp1 += 2 * KT; gp2 += 2 * KT; gp3 += 2 * KT;
        wt += 2 * KT * ODIM;
    }
    {   // tile NT-2 (buf0); outstanding {NT-2,NT-1} -> vmcnt(4) ok
        asm volatile("s_waitcnt vmcnt(4)" ::: "memory");
        float4 x0 = rd0[0 ^ sw], x1 = rd0[1 ^ sw];
        float4 x2 = rd0[2 ^ sw], x3 = rd0[3 ^ sw];
        FMA16(wt);
    }
    {   // tile NT-1 (buf1); full drain before LDS reuse
        asm volatile("s_waitcnt vmcnt(0)" ::: "memory");
        float4 x0 = rd1[0 ^ sw], x1 = rd1[1 ^ sw];
        float4 x2 = rd1[2 ^ sw], x3 = rd1[3 ^ sw];
        FMA16(wt + KT * ODIM);
    }
#undef ISSUE
#undef FMA16

    // cross-wave reduce (only barriers in the kernel)
    __syncthreads();
    #pragma unroll
    for (int o = 0; o < ODIM; ++o) sm.part[wv][o][lane] = acc[o];
    __syncthreads();

    float* __restrict__ pb = pout + ((size_t)kb * BATCH + rowbase) * ODIM;
    #pragma unroll
    for (int i = 0; i < 8; ++i) {
        int j = tid + THREADS * i;        // j = r*32 + o, fully coalesced
        int r = j >> 5, o = j & 31;
        float s = (sm.part[0][o][r] + sm.part[1][o][r]) +
                  (sm.part[2][o][r] + sm.part[3][o][r]);
        pb[j] = s;
    }
}

// ---------------------------------------------------------------------------
// Final: out = (p0+p1+p2+p3) * scale
// ---------------------------------------------------------------------------
__global__ void reduce_kernel(const float* __restrict__ pout,
                              const float* __restrict__ scale_p,
                              float* __restrict__ out) {
    const int STRIDE = BATCH * ODIM / 4;
    int i = blockIdx.x * 256 + threadIdx.x;       // grid 512 x 256
    const float s = scale_p[0];
    const float4* p = (const float4*)pout;
    float4 a = p[i], b = p[i + STRIDE], c = p[i + 2 * STRIDE], d = p[i + 3 * STRIDE];
    float4 r;
    r.x = ((a.x + b.x) + (c.x + d.x)) * s;
    r.y = ((a.y + b.y) + (c.y + d.y)) * s;
    r.z = ((a.z + b.z) + (c.z + d.z)) * s;
    r.w = ((a.w + b.w) + (c.w + d.w)) * s;
    ((float4*)out)[i] = r;
}

// ---------------------------------------------------------------------------
extern "C" void kernel_launch(void* const* d_in, const int* in_sizes, int n_in,
                              void* d_out, int out_size, void* d_ws, size_t ws_size,
                              hipStream_t stream) {
    const float* x = (const float*)d_in[0];
    const float* w = (const float*)d_in[1];
    float* out = (float*)d_out;

    float* wsf     = (float*)d_ws;
    float* partial = wsf;                       // 1024 floats
    float* scale   = wsf + 1024;                // 1 float
    float* bwT     = wsf + 2048;                // 262144 floats (1 MiB)
    float* pout    = wsf + 2048 + ODIM * KDIM;  // SK * 524288 floats (8 MiB)

    prep_kernel<<<1024, 256, 0, stream>>>(w, bwT, partial);
    scale_kernel<<<1, 256, 0, stream>>>(partial, scale);
    main_kernel<<<(BATCH / 64) * SK, THREADS, 0, stream>>>(x, bwT, pout);
    reduce_kernel<<<BATCH * ODIM / 4 / 256, 256, 0, stream>>>(pout, scale, out);
}